// Round 24
// baseline (44.386 us; speedup 1.0000x reference)
//
#include <hip/hip_runtime.h>
#include <math.h>

#define C2 2.8853900817779268f   // 2*log2(e)

typedef __attribute__((address_space(3))) unsigned int       lds_u32;
typedef const __attribute__((address_space(1))) unsigned int g_u32;

__device__ __forceinline__ void stage16(const float* g, float* l) {
    __builtin_amdgcn_global_load_lds((g_u32*)g, (lds_u32*)l, 16, 0, 0);
}

// ---------------- score kernel ----------------
// 512 blocks x 512 thr; block = (b, k-half, 32-row-group); 80 KB LDS ->
// 2 blocks/CU = 4 waves/SIMD. Phase-homogeneous: stage 64KB, 1 barrier,
// pure score loop, 8 coalesced stores. Scores written pre-scaled by -C2.
__global__ __launch_bounds__(512, 4) void score_kernel(
    const float* __restrict__ q_g, const float* __restrict__ k_g,
    const float* __restrict__ w_g, float* __restrict__ sc_ws)
{
    __shared__ float kbuf[16384];   // 64 KB: Ek[t2][g32][rot64][hi4]
    __shared__ float sEq[4096];     // 16 KB: 8 waves x Eq[4][128]

    const int tid  = threadIdx.x;
    const int lane = tid & 63;
    const int wv   = __builtin_amdgcn_readfirstlane(tid >> 6);  // 0..7

    const int xcd = blockIdx.x & 7;
    const int sub = blockIdx.x >> 3;          // 0..63
    const int b   = (xcd << 2) + (sub >> 4);  // 4 batches per XCD
    const int rem = sub & 15;
    const int kh  = rem >> 3;                 // k-half
    const int rg  = rem & 7;                  // row-group
    const int qr0 = (rg << 5) + (wv << 2);    // wave's 4 q rows

    float* strip = sEq + (wv << 9);           // Eq[4][128], wave-private

    // Eq = exp2(C2*q) for the wave's 4 rows
    {
        const float* qb = q_g + (size_t)(b * 256 + qr0) * 128;
        #pragma unroll
        for (int j = 0; j < 2; ++j) {
            int f = lane + (j << 6);
            int r = f >> 5, c = f & 31;
            float4 qv = *(const float4*)(qb + (r << 7) + (c << 2));
            float4 E;
            E.x = __builtin_amdgcn_exp2f(C2 * qv.x);
            E.y = __builtin_amdgcn_exp2f(C2 * qv.y);
            E.z = __builtin_amdgcn_exp2f(C2 * qv.z);
            E.w = __builtin_amdgcn_exp2f(C2 * qv.w);
            *(float4*)&strip[(r << 7) + (c << 2)] = E;
        }
    }

    // stage K rows [kh*128, +128): load -> exp2 -> rotation-swizzled kbuf
    {
        const float4* kg4 = (const float4*)(k_g + (size_t)b * 32768 + (kh << 14));
        #pragma unroll
        for (int j = 0; j < 8; ++j) {
            int f = tid + (j << 9);            // 0..4095 float4s
            float4 kv = kg4[f];
            int k = f >> 5, g = f & 31;        // k 0..127, g 0..31
            float4 E;
            E.x = __builtin_amdgcn_exp2f(C2 * kv.x);
            E.y = __builtin_amdgcn_exp2f(C2 * kv.y);
            E.z = __builtin_amdgcn_exp2f(C2 * kv.z);
            E.w = __builtin_amdgcn_exp2f(C2 * kv.w);
            int rot = ((k & 63) + g) & 63;
            *(float4*)&kbuf[((k >> 6) << 13) + (g << 8) + (rot << 2)] = E;
        }
    }
    __syncthreads();    // the only barrier

    // score: g outer; 8 accumulators [t2][r4]
    float s[2][4];
    #pragma unroll
    for (int t = 0; t < 2; ++t)
        #pragma unroll
        for (int r = 0; r < 4; ++r) s[t][r] = 0.f;

    #pragma unroll 4
    for (int g = 0; g < 32; ++g) {
        float4 w4 = *(const float4*)(w_g + (g << 2));         // scalar K$ (uniform)
        float4 e0 = *(const float4*)&strip[g << 2];
        float4 e1 = *(const float4*)&strip[128 + (g << 2)];
        float4 e2 = *(const float4*)&strip[256 + (g << 2)];
        float4 e3 = *(const float4*)&strip[384 + (g << 2)];
        const int rot = (((lane + g) & 63) << 2) + (g << 8);
        #pragma unroll
        for (int t = 0; t < 2; ++t) {
            float4 k4 = *(const float4*)&kbuf[(t << 13) + rot];
            #define RB(E, S)                                                   \
            {                                                                  \
                float d0 = fmaf(E.x, k4.x, 1.f), d1 = fmaf(E.y, k4.y, 1.f);    \
                float d2 = fmaf(E.z, k4.z, 1.f), d3 = fmaf(E.w, k4.w, 1.f);    \
                float P01 = d0 * d1, P23 = d2 * d3;                            \
                float N01 = fmaf(w4.x, d1, w4.y * d0);                         \
                float N23 = fmaf(w4.z, d3, w4.w * d2);                         \
                float num = fmaf(N01, P23, N23 * P01);                         \
                S = fmaf(num, __builtin_amdgcn_rcpf(P01 * P23), S);            \
            }
            RB(e0, s[t][0])
            RB(e1, s[t][1])
            RB(e2, s[t][2])
            RB(e3, s[t][3])
            #undef RB
        }
    }

    // write scores (pre-scaled by -C2); lane = k within tile, coalesced
    #pragma unroll
    for (int r = 0; r < 4; ++r) {
        float* br = sc_ws + (size_t)(b * 256 + qr0 + r) * 256 + (kh << 7) + lane;
        br[0]  = -C2 * s[0][r];
        br[64] = -C2 * s[1][r];
    }
}

// ---------------- softmax + PV kernel ----------------
// 256 blocks x 512 thr (8 waves x 4 rows), 160 KB LDS. V[b] staged via
// global_load_lds into kbuf (latency hidden under softmax); no-max softmax
// (scores bounded, r23-validated); PV entirely on the LDS pipe.
__global__ __launch_bounds__(512) void pv_kernel(
    const float* __restrict__ sc_ws, const float* __restrict__ v_g,
    float* __restrict__ out)
{
    __shared__ float kbuf[32768];   // 128 KB: V[256][128]
    __shared__ float sB[8192];      //  32 KB: 8 waves x attn[4][256]

    const int tid  = threadIdx.x;
    const int lane = tid & 63;
    const int wv   = __builtin_amdgcn_readfirstlane(tid >> 6);  // 0..7

    const int xcd = blockIdx.x & 7;
    const int sub = blockIdx.x >> 3;          // 0..31
    const int b   = (xcd << 2) + (sub >> 3);  // same XCD mapping as score kernel
    const int qr0 = ((sub & 7) << 5) + (wv << 2);

    float* strip = sB + (wv << 10);

    // stage V[b] (128 KB) async: 16 x 1KB chunks per wave (zero VGPR)
    {
        const float* vb = v_g + (size_t)b * 32768;
        #pragma unroll
        for (int c = 0; c < 16; ++c) {
            int chunk = (wv << 4) + c;
            stage16(vb + (chunk << 8) + (lane << 2), kbuf + (chunk << 8));
        }
    }

    // softmax (no-max; scores already x(-C2)) — overlaps V-stage latency
    #pragma unroll
    for (int r = 0; r < 4; ++r) {
        const float* srow = sc_ws + (size_t)(b * 256 + qr0 + r) * 256;
        float4 sv = *(const float4*)(srow + (lane << 2));     // 1KB coalesced, L2-hot
        float p0 = __builtin_amdgcn_exp2f(sv.x);
        float p1 = __builtin_amdgcn_exp2f(sv.y);
        float p2 = __builtin_amdgcn_exp2f(sv.z);
        float p3 = __builtin_amdgcn_exp2f(sv.w);
        float sum = (p0 + p1) + (p2 + p3);
        #pragma unroll
        for (int off = 32; off; off >>= 1) sum += __shfl_xor(sum, off);
        float inv = __builtin_amdgcn_rcpf(sum);
        float4 at; at.x = p0 * inv; at.y = p1 * inv; at.z = p2 * inv; at.w = p3 * inv;
        *(float4*)&strip[(r << 8) + (lane << 2)] = at;        // wave-private
    }
    __syncthreads();    // drains V stage (vmcnt) + publishes kbuf

    // PV entirely on the LDS pipe: lane = h-pair (h = 2*lane, 2*lane+1)
    float2 o0, o1, o2, o3;
    o0.x = o0.y = o1.x = o1.y = 0.f;
    o2.x = o2.y = o3.x = o3.y = 0.f;
    #pragma unroll 4
    for (int j4 = 0; j4 < 64; ++j4) {
        float4 a0 = *(const float4*)(strip + (j4 << 2));      // row bcasts
        float4 a1 = *(const float4*)(strip + 256 + (j4 << 2));
        float4 a2 = *(const float4*)(strip + 512 + (j4 << 2));
        float4 a3 = *(const float4*)(strip + 768 + (j4 << 2));
        #pragma unroll
        for (int i = 0; i < 4; ++i) {
            float2 v2 = *(const float2*)&kbuf[(((j4 << 2) + i) << 7) + (lane << 1)];
            float c0 = (&a0.x)[i], c1 = (&a1.x)[i], c2 = (&a2.x)[i], c3 = (&a3.x)[i];
            o0.x = fmaf(c0, v2.x, o0.x); o0.y = fmaf(c0, v2.y, o0.y);
            o1.x = fmaf(c1, v2.x, o1.x); o1.y = fmaf(c1, v2.y, o1.y);
            o2.x = fmaf(c2, v2.x, o2.x); o2.y = fmaf(c2, v2.y, o2.y);
            o3.x = fmaf(c3, v2.x, o3.x); o3.y = fmaf(c3, v2.y, o3.y);
        }
    }

    float* ob = out + (size_t)(b * 256 + qr0) * 128 + (lane << 1);
    *(float2*)(ob)       = o0;
    *(float2*)(ob + 128) = o1;
    *(float2*)(ob + 256) = o2;
    *(float2*)(ob + 384) = o3;
}

extern "C" void kernel_launch(void* const* d_in, const int* in_sizes, int n_in,
                              void* d_out, int out_size, void* d_ws, size_t ws_size,
                              hipStream_t stream) {
    const float* q = (const float*)d_in[0];
    const float* k = (const float*)d_in[1];
    const float* v = (const float*)d_in[2];
    const float* w = (const float*)d_in[3];
    float* out = (float*)d_out;
    float* sc  = (float*)d_ws;                 // 32*256*256*4 = 8 MB (exactly ws, proven r12)
    score_kernel<<<512, 512, 0, stream>>>(q, k, w, sc);
    pv_kernel<<<256, 512, 0, stream>>>(sc, v, out);
}

// Round 25
// 42.343 us; speedup vs baseline: 1.0482x; 1.0482x over previous
//
#include <hip/hip_runtime.h>
#include <math.h>

#define C2 2.8853900817779268f   // 2*log2(e)

typedef __attribute__((address_space(3))) unsigned int       lds_u32;
typedef const __attribute__((address_space(1))) unsigned int g_u32;

__device__ __forceinline__ void stage16(const float* g, float* l) {
    __builtin_amdgcn_global_load_lds((g_u32*)g, (lds_u32*)l, 16, 0, 0);
}

// 256 blocks x 512 thr (8 waves x 4 q rows), 1 block/CU, 160 KB LDS.
// r23 structure + A/B software-pipelined score loop with sched_barrier(0)
// fences so the compiler cannot sink the prefetched LDS loads back to their
// use sites (r22's failure). Each set's 9 loads drain under the other set's
// ~440-cyc compute block.
__global__ __launch_bounds__(512) void addattn_kernel(
    const float* __restrict__ q_g, const float* __restrict__ k_g,
    const float* __restrict__ v_g, const float* __restrict__ w_g,
    float* __restrict__ out)
{
    __shared__ float kbuf[32768];   // 128 KB: Ek[t4][g32][rot64][hi4] -> V[256][128]
    __shared__ float sB[8192];      //  32 KB: 8 waves x 1024f strip (Eq[4][128]|w -> attn[4][256])

    const int tid  = threadIdx.x;
    const int lane = tid & 63;
    const int wv   = __builtin_amdgcn_readfirstlane(tid >> 6);  // 0..7 uniform

    const int xcd = blockIdx.x & 7;
    const int sub = blockIdx.x >> 3;          // 0..31
    const int b   = (xcd << 2) + (sub >> 3);
    const int qr0 = ((sub & 7) << 5) + (wv << 2);   // wave's 4 q rows

    float* strip = sB + (wv << 10);   // 1024 floats, wave-private

    // ---- strip: w copy at [512..640), Eq[4][128] at [0..512) ----
    if (lane < 32) *(float4*)&strip[512 + (lane << 2)] = ((const float4*)w_g)[lane];
    {
        const float* qb = q_g + (size_t)(b * 256 + qr0) * 128;
        #pragma unroll
        for (int j = 0; j < 2; ++j) {
            int f = lane + (j << 6);
            int r = f >> 5, c = f & 31;
            float4 qv = *(const float4*)(qb + (r << 7) + (c << 2));
            float4 E;
            E.x = __builtin_amdgcn_exp2f(C2 * qv.x);
            E.y = __builtin_amdgcn_exp2f(C2 * qv.y);
            E.z = __builtin_amdgcn_exp2f(C2 * qv.z);
            E.w = __builtin_amdgcn_exp2f(C2 * qv.w);
            *(float4*)&strip[(r << 7) + (c << 2)] = E;
        }
    }

    // ---- stage K[b]: load -> exp2 -> rotation-swizzled kbuf (conflict-free) ----
    {
        const float4* kg4 = (const float4*)(k_g + (size_t)b * 32768);
        #pragma unroll
        for (int j = 0; j < 16; ++j) {
            int f = tid + (j << 9);            // 0..8191 float4s
            float4 kv = kg4[f];
            int k = f >> 5, g = f & 31;
            float4 E;
            E.x = __builtin_amdgcn_exp2f(C2 * kv.x);
            E.y = __builtin_amdgcn_exp2f(C2 * kv.y);
            E.z = __builtin_amdgcn_exp2f(C2 * kv.z);
            E.w = __builtin_amdgcn_exp2f(C2 * kv.w);
            int rot = ((k & 63) + g) & 63;
            *(float4*)&kbuf[((k >> 6) << 13) + (g << 8) + (rot << 2)] = E;
        }
    }
    __syncthreads();    // barrier 1: Ek visible

    // ---- score: A/B pipelined, fenced with sched_barrier(0) ----
    float s[4][4];
    #pragma unroll
    for (int t = 0; t < 4; ++t)
        #pragma unroll
        for (int r = 0; r < 4; ++r) s[t][r] = 0.f;

    #define LOADSET(G, W, E0, E1, E2, E3, K0, K1, K2, K3)                      \
    {                                                                          \
        const int g_ = (G);                                                    \
        W  = *(const float4*)&strip[512 + (g_ << 2)];                          \
        E0 = *(const float4*)&strip[g_ << 2];                                  \
        E1 = *(const float4*)&strip[128 + (g_ << 2)];                          \
        E2 = *(const float4*)&strip[256 + (g_ << 2)];                          \
        E3 = *(const float4*)&strip[384 + (g_ << 2)];                          \
        const int rot_ = (((lane + g_) & 63) << 2) + (g_ << 8);                \
        K0 = *(const float4*)&kbuf[rot_];                                      \
        K1 = *(const float4*)&kbuf[8192 + rot_];                               \
        K2 = *(const float4*)&kbuf[16384 + rot_];                              \
        K3 = *(const float4*)&kbuf[24576 + rot_];                              \
    }
    #define RB(E, K4, S)                                                       \
    {                                                                          \
        float d0 = fmaf(E.x, K4.x, 1.f), d1 = fmaf(E.y, K4.y, 1.f);            \
        float d2 = fmaf(E.z, K4.z, 1.f), d3 = fmaf(E.w, K4.w, 1.f);            \
        float P01 = d0 * d1, P23 = d2 * d3;                                    \
        float N01 = fmaf(W_.x, d1, W_.y * d0);                                 \
        float N23 = fmaf(W_.z, d3, W_.w * d2);                                 \
        float num = fmaf(N01, P23, N23 * P01);                                 \
        S = fmaf(num, __builtin_amdgcn_rcpf(P01 * P23), S);                    \
    }
    #define COMPUTE(W, E0, E1, E2, E3, K0, K1, K2, K3)                         \
    {                                                                          \
        float4 W_ = W;                                                         \
        RB(E0, K0, s[0][0]) RB(E1, K0, s[0][1]) RB(E2, K0, s[0][2]) RB(E3, K0, s[0][3]) \
        RB(E0, K1, s[1][0]) RB(E1, K1, s[1][1]) RB(E2, K1, s[1][2]) RB(E3, K1, s[1][3]) \
        RB(E0, K2, s[2][0]) RB(E1, K2, s[2][1]) RB(E2, K2, s[2][2]) RB(E3, K2, s[2][3]) \
        RB(E0, K3, s[3][0]) RB(E1, K3, s[3][1]) RB(E2, K3, s[3][2]) RB(E3, K3, s[3][3]) \
    }

    {
        float4 wA, e0A, e1A, e2A, e3A, k0A, k1A, k2A, k3A;
        float4 wB, e0B, e1B, e2B, e3B, k0B, k1B, k2B, k3B;
        LOADSET(0, wA, e0A, e1A, e2A, e3A, k0A, k1A, k2A, k3A)
        #pragma unroll 1
        for (int gp = 0; gp < 16; ++gp) {
            const int g0 = gp << 1;
            LOADSET(g0 + 1, wB, e0B, e1B, e2B, e3B, k0B, k1B, k2B, k3B)
            __builtin_amdgcn_sched_barrier(0);   // pin B-loads above A-compute
            COMPUTE(wA, e0A, e1A, e2A, e3A, k0A, k1A, k2A, k3A)
            if (gp < 15)
                LOADSET(g0 + 2, wA, e0A, e1A, e2A, e3A, k0A, k1A, k2A, k3A)
            __builtin_amdgcn_sched_barrier(0);   // pin A-loads above B-compute
            COMPUTE(wB, e0B, e1B, e2B, e3B, k0B, k1B, k2B, k3B)
        }
    }
    #undef COMPUTE
    #undef RB
    #undef LOADSET

    // ---- no-max softmax per row (scores bounded; r23-validated) ----
    #pragma unroll
    for (int r = 0; r < 4; ++r) {
        float p0 = __builtin_amdgcn_exp2f(-C2 * s[0][r]);
        float p1 = __builtin_amdgcn_exp2f(-C2 * s[1][r]);
        float p2 = __builtin_amdgcn_exp2f(-C2 * s[2][r]);
        float p3 = __builtin_amdgcn_exp2f(-C2 * s[3][r]);
        float sum = (p0 + p1) + (p2 + p3);
        #pragma unroll
        for (int off = 32; off; off >>= 1) sum += __shfl_xor(sum, off);
        float inv = __builtin_amdgcn_rcpf(sum);
        strip[(r << 8) + lane]       = p0 * inv;
        strip[(r << 8) + 64 + lane]  = p1 * inv;
        strip[(r << 8) + 128 + lane] = p2 * inv;
        strip[(r << 8) + 192 + lane] = p3 * inv;
    }

    __syncthreads();    // barrier 2: all Ek reads done -> kbuf reusable

    // ---- restage V[b] (128 KB) into kbuf via global_load_lds (zero VGPR) ----
    {
        const float* vb = v_g + (size_t)b * 32768;
        #pragma unroll
        for (int c = 0; c < 16; ++c) {
            int chunk = (wv << 4) + c;
            stage16(vb + (chunk << 8) + (lane << 2), kbuf + (chunk << 8));
        }
    }
    __syncthreads();    // barrier 3: V visible

    // ---- PV on the LDS pipe: lane = h-pair (h = 2*lane, 2*lane+1) ----
    float2 o0, o1, o2, o3;
    o0.x = o0.y = o1.x = o1.y = 0.f;
    o2.x = o2.y = o3.x = o3.y = 0.f;
    #pragma unroll 4
    for (int j4 = 0; j4 < 64; ++j4) {
        float4 a0 = *(const float4*)(strip + (j4 << 2));
        float4 a1 = *(const float4*)(strip + 256 + (j4 << 2));
        float4 a2 = *(const float4*)(strip + 512 + (j4 << 2));
        float4 a3 = *(const float4*)(strip + 768 + (j4 << 2));
        #pragma unroll
        for (int i = 0; i < 4; ++i) {
            float2 v2 = *(const float2*)&kbuf[(((j4 << 2) + i) << 7) + (lane << 1)];
            float c0 = (&a0.x)[i], c1 = (&a1.x)[i], c2 = (&a2.x)[i], c3 = (&a3.x)[i];
            o0.x = fmaf(c0, v2.x, o0.x); o0.y = fmaf(c0, v2.y, o0.y);
            o1.x = fmaf(c1, v2.x, o1.x); o1.y = fmaf(c1, v2.y, o1.y);
            o2.x = fmaf(c2, v2.x, o2.x); o2.y = fmaf(c2, v2.y, o2.y);
            o3.x = fmaf(c3, v2.x, o3.x); o3.y = fmaf(c3, v2.y, o3.y);
        }
    }

    float* ob = out + (size_t)(b * 256 + qr0) * 128 + (lane << 1);
    *(float2*)(ob)       = o0;
    *(float2*)(ob + 128) = o1;
    *(float2*)(ob + 256) = o2;
    *(float2*)(ob + 384) = o3;
}

extern "C" void kernel_launch(void* const* d_in, const int* in_sizes, int n_in,
                              void* d_out, int out_size, void* d_ws, size_t ws_size,
                              hipStream_t stream) {
    const float* q = (const float*)d_in[0];
    const float* k = (const float*)d_in[1];
    const float* v = (const float*)d_in[2];
    const float* w = (const float*)d_in[3];
    float* out = (float*)d_out;
    addattn_kernel<<<256, 512, 0, stream>>>(q, k, v, w, out);
}